// Round 2
// baseline (216.505 us; speedup 1.0000x reference)
//
#include <hip/hip_runtime.h>
#include <math.h>

#define N_POINTS   32768
#define BLOCK      256
#define P          8                            // a-points per thread
#define ROWS_PER_BLOCK (P * BLOCK)              // 2048
#define ROW_BLOCKS (N_POINTS / ROWS_PER_BLOCK)  // 16
#define S          32                           // b-dimension splits
#define CHUNK_B    (N_POINTS / S)               // 1024 b-points staged per block

// ---------------------------------------------------------------------------
// Kernel 1: block (dir, rb, sb) computes, for each of its 2048 a-points, the
// min over its 1024-point b-chunk of (||b||^2 - 2 a.b); ||a||^2 is added once
// at the end (fold-out saves one VALU add per pair -> 3.5 ops/pair).
// Partial mins -> partial[sb][dir*N + i]. Deterministic (no atomics).
// ---------------------------------------------------------------------------
__global__ __launch_bounds__(BLOCK, 2) void chamfer_partial_kernel(
    const float* __restrict__ target,
    const float* __restrict__ outp,
    float* __restrict__ partial)   // [S][2*N_POINTS]
{
    const int bid = blockIdx.x;
    const int dir = bid >> 9;          // / (ROW_BLOCKS*S) = /512
    const int rem = bid & 511;
    const int rb  = rem >> 5;          // / S
    const int sb  = rem & (S - 1);

    const float* __restrict__ a = dir ? outp   : target;
    const float* __restrict__ b = dir ? target : outp;

    __shared__ float4 bs[CHUNK_B];     // (x, y, z, ||b||^2) : 16 KB

    // ---- stage b chunk into LDS ----
    const int b_base = sb * CHUNK_B;
    #pragma unroll
    for (int k = 0; k < CHUNK_B / BLOCK; ++k) {
        const int j = threadIdx.x + k * BLOCK;
        const float* bp = &b[(size_t)(b_base + j) * 3];
        const float bx = bp[0], by = bp[1], bz = bp[2];
        bs[j] = make_float4(bx, by, bz, bx * bx + by * by + bz * bz);
    }

    // ---- load my P a-points, precompute -2a and ||a||^2 ----
    float nax[P], nay[P], naz[P], an[P], m[P];
    const int a_base = rb * ROWS_PER_BLOCK + threadIdx.x;
    #pragma unroll
    for (int p = 0; p < P; ++p) {
        const float* ap = &a[(size_t)(a_base + p * BLOCK) * 3];
        const float ax = ap[0], ay = ap[1], az = ap[2];
        nax[p] = -2.0f * ax;
        nay[p] = -2.0f * ay;
        naz[p] = -2.0f * az;
        an[p]  = ax * ax + ay * ay + az * az;
        m[p]   = 3.4e38f;
    }

    __syncthreads();

    // ---- main loop: 3 FMA/pair, 1 min3 per 2 pairs (an folded out) ----
    for (int j = 0; j < CHUNK_B; j += 2) {
        const float4 b0 = bs[j];
        const float4 b1 = bs[j + 1];
        #pragma unroll
        for (int p = 0; p < P; ++p) {
            float t0 = fmaf(nax[p], b0.x, b0.w);
            t0 = fmaf(nay[p], b0.y, t0);
            t0 = fmaf(naz[p], b0.z, t0);
            float t1 = fmaf(nax[p], b1.x, b1.w);
            t1 = fmaf(nay[p], b1.y, t1);
            t1 = fmaf(naz[p], b1.z, t1);
            m[p] = fminf(fminf(m[p], t0), t1);   // -> v_min3_f32
        }
    }

    // ---- write partial mins (+ ||a||^2 re-added) ----
    #pragma unroll
    for (int p = 0; p < P; ++p) {
        partial[(size_t)sb * (2 * N_POINTS) + dir * N_POINTS +
                rb * ROWS_PER_BLOCK + p * BLOCK + threadIdx.x] = m[p] + an[p];
    }
}

// ---------------------------------------------------------------------------
// Kernel 2: min over the S partials per point, sqrt, block-level partial sums.
// 64 blocks x 256 threads covering 2*N = 65536 points (4 per thread).
// ---------------------------------------------------------------------------
__global__ __launch_bounds__(256) void chamfer_reduce_kernel(
    const float* __restrict__ partial,  // [S][2*N_POINTS]
    float* __restrict__ bsums)          // [64]
{
    const int c0 = blockIdx.x * 1024 + threadIdx.x;
    float sum = 0.0f;
    #pragma unroll
    for (int k = 0; k < 4; ++k) {
        const int c = c0 + k * 256;
        float mn = 3.4e38f;
        #pragma unroll
        for (int s = 0; s < S; ++s)
            mn = fminf(mn, partial[(size_t)s * (2 * N_POINTS) + c]);
        sum += sqrtf(fmaxf(mn, 0.0f));   // clamp: expanded form can go ~-1e-7
    }

    __shared__ float red[256];
    red[threadIdx.x] = sum;
    __syncthreads();
    #pragma unroll
    for (int off = 128; off > 0; off >>= 1) {
        if (threadIdx.x < off) red[threadIdx.x] += red[threadIdx.x + off];
        __syncthreads();
    }
    if (threadIdx.x == 0) bsums[blockIdx.x] = red[0];
}

// ---------------------------------------------------------------------------
// Kernel 3: final scalar. loss = (sum_all_sqrt / (2N)) * 10 / 1.02^(cur//20)
// ---------------------------------------------------------------------------
__global__ void chamfer_finalize_kernel(
    const float* __restrict__ bsums,    // [64]
    const int* __restrict__ curp,
    float* __restrict__ out)
{
    float v = bsums[threadIdx.x];       // 64 threads, one per block sum
    #pragma unroll
    for (int off = 32; off > 0; off >>= 1)
        v += __shfl_down(v, off);
    if (threadIdx.x == 0) {
        const int cur = curp[0];
        const float decay = powf(1.02f, (float)(cur / 20));
        out[0] = v / (float)(2 * N_POINTS) * 10.0f / decay;
    }
}

// ---------------------------------------------------------------------------
extern "C" void kernel_launch(void* const* d_in, const int* in_sizes, int n_in,
                              void* d_out, int out_size, void* d_ws, size_t ws_size,
                              hipStream_t stream) {
    const float* target = (const float*)d_in[0];
    const float* outp   = (const float*)d_in[1];
    const int*   cur    = (const int*)d_in[2];
    float*       out    = (float*)d_out;

    float* partial = (float*)d_ws;                         // S * 2N floats = 8 MB
    float* bsums   = partial + (size_t)S * 2 * N_POINTS;   // 64 floats

    chamfer_partial_kernel<<<2 * ROW_BLOCKS * S, BLOCK, 0, stream>>>(target, outp, partial);
    chamfer_reduce_kernel<<<64, 256, 0, stream>>>(partial, bsums);
    chamfer_finalize_kernel<<<1, 64, 0, stream>>>(bsums, cur, out);
}